// Round 1
// 1568.432 us; speedup vs baseline: 1.2735x; 1.2735x over previous
//
#include <hip/hip_runtime.h>
#include <stdint.h>

typedef unsigned short u16;
typedef __attribute__((ext_vector_type(8))) short bf16x8;
typedef __attribute__((ext_vector_type(4))) short s16x4;
typedef __attribute__((ext_vector_type(4))) float f32x4;

#define NTOK 49
#define NHEAD 8
#define HDIM 32
#define CH 256
#define NWIN 4096
#define MTOT (NWIN * NTOK)        /* 200704 */
#define QKV_N 768
#define ATT_SCALE 0.17677669529663687f

/* workspace byte offsets */
#define OFF_WQT_X   0u
#define OFF_WQT_R   393216u
#define OFF_WPT_X   786432u
#define OFF_WPT_R   917504u
#define OFF_BIASM   1048576u      /* biasmT[h][C][R] fp32, 76832 B */
#define OFF_MASKT   1130496u      /* maskT[w][C][R] fp32, 614656 B (ends 1745152 < 2097152) */
#define OFF_QKV_X   2097152u
#define OFF_QKV_R   310378496u    /* 2097152 + 200704*768*2 */

__device__ __forceinline__ float bf2f(u16 u) {
  unsigned int x = ((unsigned int)u) << 16;
  return __builtin_bit_cast(float, x);
}
__device__ __forceinline__ u16 f2bf(float f) {
  unsigned int x = __builtin_bit_cast(unsigned int, f);
  x = x + 0x7FFFu + ((x >> 16) & 1u);
  return (u16)(x >> 16);
}
__device__ __forceinline__ bf16x8 zero8() { bf16x8 z = {0,0,0,0,0,0,0,0}; return z; }
__device__ __forceinline__ f32x4 zero4() { f32x4 z = {0.f,0.f,0.f,0.f}; return z; }

/* LDS XOR swizzle for [row][64 col] bf16 tiles (128B row stride):
   spreads b128 column-slice reads uniformly over all 8 16B slots and
   separates write quads. Same involution on write and read side. */
__device__ __forceinline__ int swz(int row) {
  return ((row & 7) << 4) ^ (((row >> 3) & 3) << 5);
}

__device__ __forceinline__ void lds_load16(const u16* g, u16* s) {
  __builtin_amdgcn_global_load_lds(
      (const __attribute__((address_space(1))) void*)g,
      (__attribute__((address_space(3))) void*)s, 16, 0, 0);
}

/* stage a 128x32 fp32 tile (row stride 256 f32) into LDS as bf16 [128][32] */
__device__ __forceinline__ void stage_f32_tile(const float* gbase, u16* lds, int tid) {
#pragma unroll
  for (int it = 0; it < 2; ++it) {
    int f = (it * 256 + tid) * 8;
    int row = f >> 5, col = f & 31;
    const float* p = gbase + (size_t)row * 256 + col;
    float4 a = *(const float4*)p;
    float4 b = *(const float4*)(p + 4);
    u16 tmp[8] = {f2bf(a.x), f2bf(a.y), f2bf(a.z), f2bf(a.w),
                  f2bf(b.x), f2bf(b.y), f2bf(b.z), f2bf(b.w)};
    *(bf16x8*)&lds[f] = *(const bf16x8*)tmp;
  }
}

/* ---------------- prep: weight transposes + transposed bias/mask tables -- */
__global__ __launch_bounds__(256) void prep_kernel(
    const float* __restrict__ w_qkv, const float* __restrict__ w_qkv_r,
    const float* __restrict__ w_proj, const float* __restrict__ w_proj_r,
    const float* __restrict__ bias_table, const int* __restrict__ rel_idx,
    const float* __restrict__ mask,
    u16* __restrict__ wqT_x, u16* __restrict__ wqT_r,
    u16* __restrict__ wpT_x, u16* __restrict__ wpT_r,
    float* __restrict__ biasmT, float* __restrict__ maskT) {
  int id = blockIdx.x * 256 + threadIdx.x;
  if (id < 196608) {                       /* wqkvT_x: [768][256] bf16 */
    int n = id >> 8, k = id & 255;
    wqT_x[id] = f2bf(w_qkv[k * 768 + n]);
  } else if (id < 393216) {
    int t = id - 196608; int n = t >> 8, k = t & 255;
    wqT_r[t] = f2bf(w_qkv_r[k * 768 + n]);
  } else if (id < 458752) {                /* wprojT_x: [256][256] bf16 */
    int t = id - 393216; int n = t >> 8, k = t & 255;
    wpT_x[t] = f2bf(w_proj[k * 256 + n]);
  } else if (id < 524288) {
    int t = id - 458752; int n = t >> 8, k = t & 255;
    wpT_r[t] = f2bf(w_proj_r[k * 256 + n]);
  } else if (id < 524288 + 19208) {        /* biasmT[h][C(49)][R(49)] fp32 */
    int t = id - 524288;
    int h = t / 2401, nm = t % 2401;
    int Rr = nm % 49, Cc = nm / 49;
    biasmT[t] = bias_table[rel_idx[Rr * 49 + Cc] * 8 + h];
  } else if (id < 543496 + 153664) {       /* maskT[w][C(49)][R(49)] fp32 */
    int t = id - 543496;
    int w2 = t / 2401, nm = t % 2401;
    int Rr = nm % 49, Cc = nm / 49;
    maskT[t] = mask[(size_t)w2 * 2401 + Rr * 49 + Cc];
  }
}

/* ---------------- qkv GEMM: OUT[m][n] = A[m][:]·WT[n][:] + bias[n] -------- */
__global__ __launch_bounds__(256) void gemm_qkv(
    const float* __restrict__ A, const u16* __restrict__ WT,
    const float* __restrict__ bias, u16* __restrict__ OUT) {
  __shared__ __align__(16) u16 lA[128 * 32];
  __shared__ __align__(16) u16 lB[128 * 32];
  int flat = blockIdx.x;
  int xcd = flat & 7;
  int loc = flat >> 3;
  int nt = loc % 6;
  int mt = xcd * 196 + loc / 6;
  const int m0 = mt * 128, n0 = nt * 128;
  const int tid = threadIdx.x;
  const int w = tid >> 6, l = tid & 63;
  const int quad = l >> 4, r = l & 15;
  const int wm = (w & 1) * 64, wn = (w >> 1) * 64;

  f32x4 acc[4][4];
#pragma unroll
  for (int i = 0; i < 4; ++i)
#pragma unroll
    for (int j = 0; j < 4; ++j) acc[i][j] = zero4();

  for (int ks = 0; ks < 8; ++ks) {
    const int k0 = ks * 32;
#pragma unroll
    for (int cc = 0; cc < 2; ++cc) {
      int c = w * 2 + cc;
      int f = c * 512 + l * 8;
      int row = f >> 5, col = f & 31;
      lds_load16(WT + (size_t)(n0 + row) * 256 + k0 + col, &lB[c * 512]);
    }
    stage_f32_tile(A + (size_t)m0 * 256 + k0, lA, tid);
    __syncthreads();
    bf16x8 af[4], bfr[4];
#pragma unroll
    for (int t = 0; t < 4; ++t) af[t] = *(const bf16x8*)&lA[(wm + 16 * t + r) * 32 + quad * 8];
#pragma unroll
    for (int t = 0; t < 4; ++t) bfr[t] = *(const bf16x8*)&lB[(wn + 16 * t + r) * 32 + quad * 8];
#pragma unroll
    for (int i = 0; i < 4; ++i)
#pragma unroll
      for (int j = 0; j < 4; ++j)
        acc[i][j] = __builtin_amdgcn_mfma_f32_16x16x32_bf16(af[i], bfr[j], acc[i][j], 0, 0, 0);
    __syncthreads();
  }
#pragma unroll
  for (int j = 0; j < 4; ++j) {
    int col = n0 + wn + 16 * j + r;
    float bv = bias[col];
#pragma unroll
    for (int i = 0; i < 4; ++i) {
      int row0 = m0 + wm + 16 * i + quad * 4;
#pragma unroll
      for (int t = 0; t < 4; ++t)
        OUT[(size_t)(row0 + t) * QKV_N + col] = f2bf(acc[i][j][t] + bv);
    }
  }
}

/* ---------------- fused cross attention, 1 task per wave ------------------ */
/* Swapped QK^T (S^T in registers): softmax kk-reduce = in-lane + 2 shfl.    */
/* V loaded coalesced, transposed into swizzled LDS; P via ds_write_b64.     */
__global__ __launch_bounds__(256, 3) void attn_kernel(
    const u16* __restrict__ qkv_x, const u16* __restrict__ qkv_r,
    const float* __restrict__ maskT, const float* __restrict__ biasmT,
    float* __restrict__ out) {
  __shared__ __align__(16) u16 Pbuf[4][64 * 64];   /* per-wave P  (bf16, swz) */
  __shared__ __align__(16) u16 VTbuf[4][32 * 64];  /* per-wave V^T (bf16, swz)*/
  /* XCD-keeping decode: 4 sibling blocks of one window land on one XCD */
  const int n_ = blockIdx.x;
  const int xcd = n_ & 7;
  const int q_ = n_ >> 3;
  const int g = q_ & 3;
  const int b = (q_ >> 2) * 8 + xcd;
  const int tid = threadIdx.x;
  const int w = tid >> 6, l = tid & 63;
  const int quad = l >> 4, r = l & 15;
  u16* Pw = Pbuf[w];
  u16* VTw = VTbuf[w];
  const float* mkT = maskT + (size_t)(b & 63) * (NTOK * NTOK);

  const int task = g * 4 + w;       /* 16 tasks: (out-stream, head) */
  const int sout = task >> 3;
  const int h = task & 7;
  const u16* qsrc = sout ? qkv_x : qkv_r;
  const u16* kvsrc = sout ? qkv_r : qkv_x;
  float* op = out + (size_t)sout * ((size_t)MTOT * CH);

  /* K and Q fragments (guarded); rows = 16t + r */
  bf16x8 kf[4], qf[4];
#pragma unroll
  for (int t = 0; t < 4; ++t) {
    int m = 16 * t + r;
    if (m < NTOK) {
      kf[t] = *(const bf16x8*)&kvsrc[(size_t)(b * NTOK + m) * QKV_N + 256 + h * HDIM + quad * 8];
      qf[t] = *(const bf16x8*)&qsrc [(size_t)(b * NTOK + m) * QKV_N +       h * HDIM + quad * 8];
    } else { kf[t] = zero8(); qf[t] = zero8(); }
  }

  /* S^T tiles: acc[i][j] has rows kk=16i+quad*4+t, cols qq=16j+r */
  f32x4 acc[4][4];
#pragma unroll
  for (int i = 0; i < 4; ++i)
#pragma unroll
    for (int j = 0; j < 4; ++j) acc[i][j] = zero4();
  __builtin_amdgcn_s_setprio(1);
#pragma unroll
  for (int i = 0; i < 4; ++i)
#pragma unroll
    for (int j = 0; j < 4; ++j)
      acc[i][j] = __builtin_amdgcn_mfma_f32_16x16x32_bf16(kf[i], qf[j], acc[i][j], 0, 0, 0);
  __builtin_amdgcn_s_setprio(0);

  /* issue V loads now: latency hides under bias/softmax */
  bf16x8 vl[4];
#pragma unroll
  for (int t = 0; t < 4; ++t) {
    int m = 16 * t + r;
    if (m < NTOK)
      vl[t] = *(const bf16x8*)&kvsrc[(size_t)(b * NTOK + m) * QKV_N + 512 + h * HDIM + quad * 8];
    else vl[t] = zero8();
  }

  /* scale + bias + mask (transposed tables: lane-contiguous in R) */
  const float* bT = biasmT + h * (NTOK * NTOK);
#pragma unroll
  for (int i = 0; i < 4; ++i)
#pragma unroll
    for (int t = 0; t < 4; ++t) {
      int Cc = 16 * i + quad * 4 + t;              /* kk */
      bool cv = (i < 3) || (Cc < NTOK);
#pragma unroll
      for (int j = 0; j < 4; ++j) {
        int Rr = 16 * j + r;                       /* qq */
        bool rv = (j < 3) || (Rr < NTOK);
        if (cv && rv) {
          int idx = Cc * NTOK + Rr;
          acc[i][j][t] = acc[i][j][t] * ATT_SCALE + bT[idx] + mkT[idx];
        } else {
          acc[i][j][t] = -1e30f;
        }
      }
    }

  /* softmax over kk for each qq=16j+r: 15 in-lane + 2 shfl_xor */
  float mx[4], rs[4], inv[4];
#pragma unroll
  for (int j = 0; j < 4; ++j) {
    float m2 = acc[0][j][0];
#pragma unroll
    for (int i = 0; i < 4; ++i)
#pragma unroll
      for (int t = 0; t < 4; ++t) m2 = fmaxf(m2, acc[i][j][t]);
    m2 = fmaxf(m2, __shfl_xor(m2, 16, 64));
    m2 = fmaxf(m2, __shfl_xor(m2, 32, 64));
    mx[j] = m2;
  }
#pragma unroll
  for (int i = 0; i < 4; ++i)
#pragma unroll
    for (int j = 0; j < 4; ++j)
#pragma unroll
      for (int t = 0; t < 4; ++t)
        acc[i][j][t] = __expf(acc[i][j][t] - mx[j]);  /* pad cols -> exact 0 */
#pragma unroll
  for (int j = 0; j < 4; ++j) {
    float s2 = 0.f;
#pragma unroll
    for (int i = 0; i < 4; ++i)
#pragma unroll
      for (int t = 0; t < 4; ++t) s2 += acc[i][j][t];
    s2 += __shfl_xor(s2, 16, 64);
    s2 += __shfl_xor(s2, 32, 64);
    rs[j] = s2;
    inv[j] = 1.0f / s2;
  }

  /* V^T into swizzled LDS (vl arrived by now) */
#pragma unroll
  for (int t = 0; t < 4; ++t)
#pragma unroll
    for (int jj = 0; jj < 8; ++jj) {
      int hd = quad * 8 + jj;
      int tok = 16 * t + r;
      int addr = ((hd << 7) + (tok << 1)) ^ swz(hd);
      *(u16*)((char*)VTw + addr) = (u16)vl[t][jj];
    }

  /* P (unnormalized exp, bf16) into swizzled LDS: packed ds_write_b64 */
#pragma unroll
  for (int j = 0; j < 4; ++j) {
    int qq = 16 * j + r;
#pragma unroll
    for (int i = 0; i < 4; ++i) {
      int kk0 = 16 * i + quad * 4;
      s16x4 pk;
#pragma unroll
      for (int t = 0; t < 4; ++t) pk[t] = (short)f2bf(acc[i][j][t]);
      int addr = ((qq << 7) + (kk0 << 1)) ^ swz(qq);
      *(s16x4*)((char*)Pw + addr) = pk;
    }
  }

  /* PV: rows=q tok (4 tiles), cols=hd (2 tiles), K=64 tok (2 steps) */
  f32x4 acc2[4][2];
#pragma unroll
  for (int i = 0; i < 4; ++i) { acc2[i][0] = zero4(); acc2[i][1] = zero4(); }
#pragma unroll
  for (int ks = 0; ks < 2; ++ks) {
    bf16x8 pf[4], vf[2];
    int cbyte = (ks * 32 + quad * 8) << 1;
#pragma unroll
    for (int i = 0; i < 4; ++i) {
      int row = 16 * i + r;
      pf[i] = *(const bf16x8*)((const char*)Pw + (((row << 7) + cbyte) ^ swz(row)));
    }
#pragma unroll
    for (int n2 = 0; n2 < 2; ++n2) {
      int row = 16 * n2 + r;
      vf[n2] = *(const bf16x8*)((const char*)VTw + (((row << 7) + cbyte) ^ swz(row)));
    }
    __builtin_amdgcn_s_setprio(1);
#pragma unroll
    for (int i = 0; i < 4; ++i)
#pragma unroll
      for (int n2 = 0; n2 < 2; ++n2)
        acc2[i][n2] = __builtin_amdgcn_mfma_f32_16x16x32_bf16(pf[i], vf[n2], acc2[i][n2], 0, 0, 0);
    __builtin_amdgcn_s_setprio(0);
  }

  /* epilogue: divide by row-sum (broadcast via width-16 shfl), store fp32 */
#pragma unroll
  for (int i = 0; i < 4; ++i) {
#pragma unroll
    for (int t = 0; t < 4; ++t) {
      int R = 16 * i + quad * 4 + t;
      float sinv = __shfl(inv[i], quad * 4 + t, 16);
      if (R < NTOK) {
#pragma unroll
        for (int n2 = 0; n2 < 2; ++n2)
          op[(size_t)(b * NTOK + R) * CH + h * HDIM + 16 * n2 + r] = acc2[i][n2][t] * sinv;
      }
    }
  }
}

/* ---------------- proj GEMM, in-place on d_out (block owns its 128 rows) - */
__global__ __launch_bounds__(256) void gemm_proj(
    const u16* __restrict__ WT_x, const u16* __restrict__ WT_r,
    const float* __restrict__ bias_x, const float* __restrict__ bias_r,
    float* __restrict__ out) {
  __shared__ __align__(16) u16 lA[128 * 32];
  __shared__ __align__(16) u16 lB[256 * 32];
  const int s = blockIdx.y;
  const u16* WT = s ? WT_r : WT_x;
  const float* bias = s ? bias_r : bias_x;
  float* IO = out + (size_t)s * ((size_t)MTOT * CH);
  const int m0 = blockIdx.x * 128;
  const int tid = threadIdx.x;
  const int w = tid >> 6, l = tid & 63;
  const int quad = l >> 4, r = l & 15;
  const int wm = (w & 1) * 64, wn = (w >> 1) * 128;

  f32x4 acc[4][8];
#pragma unroll
  for (int i = 0; i < 4; ++i)
#pragma unroll
    for (int j = 0; j < 8; ++j) acc[i][j] = zero4();

  for (int ks = 0; ks < 8; ++ks) {
    const int k0 = ks * 32;
#pragma unroll
    for (int cc = 0; cc < 4; ++cc) {
      int c = w * 4 + cc;
      int f = c * 512 + l * 8;
      int row = f >> 5, col = f & 31;
      lds_load16(WT + (size_t)row * 256 + k0 + col, &lB[c * 512]);
    }
    stage_f32_tile(IO + (size_t)m0 * 256 + k0, lA, tid);
    __syncthreads();
    bf16x8 af[4], bfr[8];
#pragma unroll
    for (int t = 0; t < 4; ++t) af[t] = *(const bf16x8*)&lA[(wm + 16 * t + r) * 32 + quad * 8];
#pragma unroll
    for (int t = 0; t < 8; ++t) bfr[t] = *(const bf16x8*)&lB[(wn + 16 * t + r) * 32 + quad * 8];
#pragma unroll
    for (int i = 0; i < 4; ++i)
#pragma unroll
      for (int j = 0; j < 8; ++j)
        acc[i][j] = __builtin_amdgcn_mfma_f32_16x16x32_bf16(af[i], bfr[j], acc[i][j], 0, 0, 0);
    __syncthreads();
  }
#pragma unroll
  for (int j = 0; j < 8; ++j) {
    int col = wn + 16 * j + r;
    float bv = bias[col];
#pragma unroll
    for (int i = 0; i < 4; ++i) {
      int row0 = m0 + wm + 16 * i + quad * 4;
#pragma unroll
      for (int t = 0; t < 4; ++t)
        IO[(size_t)(row0 + t) * 256 + col] = acc[i][j][t] + bv;
    }
  }
}

extern "C" void kernel_launch(void* const* d_in, const int* in_sizes, int n_in,
                              void* d_out, int out_size, void* d_ws, size_t ws_size,
                              hipStream_t stream) {
  const float* x        = (const float*)d_in[0];
  const float* rgb      = (const float*)d_in[1];
  const float* mask     = (const float*)d_in[2];
  const float* w_qkv    = (const float*)d_in[3];
  const float* b_qkv    = (const float*)d_in[4];
  const float* w_qkv_r  = (const float*)d_in[5];
  const float* b_qkv_r  = (const float*)d_in[6];
  const float* btab     = (const float*)d_in[7];
  const float* w_proj   = (const float*)d_in[8];
  const float* b_proj   = (const float*)d_in[9];
  const float* w_proj_r = (const float*)d_in[10];
  const float* b_proj_r = (const float*)d_in[11];
  const int* rel_idx    = (const int*)d_in[12];

  char* ws = (char*)d_ws;
  u16* wqT_x  = (u16*)(ws + OFF_WQT_X);
  u16* wqT_r  = (u16*)(ws + OFF_WQT_R);
  u16* wpT_x  = (u16*)(ws + OFF_WPT_X);
  u16* wpT_r  = (u16*)(ws + OFF_WPT_R);
  float* biasmT = (float*)(ws + OFF_BIASM);
  float* maskT  = (float*)(ws + OFF_MASKT);
  u16* qkv_x  = (u16*)(ws + OFF_QKV_X);
  u16* qkv_r  = (u16*)(ws + OFF_QKV_R);
  float* outp = (float*)d_out;

  prep_kernel<<<2724, 256, 0, stream>>>(w_qkv, w_qkv_r, w_proj, w_proj_r,
                                        btab, rel_idx, mask,
                                        wqT_x, wqT_r, wpT_x, wpT_r, biasmT, maskT);
  gemm_qkv<<<9408, 256, 0, stream>>>(x, wqT_x, b_qkv, qkv_x);
  gemm_qkv<<<9408, 256, 0, stream>>>(rgb, wqT_r, b_qkv_r, qkv_r);
  attn_kernel<<<NWIN * 4, 256, 0, stream>>>(qkv_x, qkv_r, maskT, biasmT, outp);
  gemm_proj<<<dim3(1568, 2), 256, 0, stream>>>(wpT_x, wpT_r, b_proj, b_proj_r, outp);
}